// Round 3
// baseline (190.159 us; speedup 1.0000x reference)
//
#include <hip/hip_runtime.h>

#define EPS 2e-5f

using short8  = __attribute__((ext_vector_type(8))) short;
using floatx4 = __attribute__((ext_vector_type(4))) float;

// round-to-nearest-even fp32 -> bf16 bits
static __device__ inline unsigned short f2bf(float f) {
    unsigned u = __float_as_uint(f);
    u += 0x7fffu + ((u >> 16) & 1u);
    return (unsigned short)(u >> 16);
}
static __device__ inline float bf2f(short s) {
    return __uint_as_float(((unsigned)(unsigned short)s) << 16);
}
static __device__ inline short8 scale8(short8 v, float sc) {
    short8 r;
    #pragma unroll
    for (int e = 0; e < 8; ++e) r[e] = (short)f2bf(bf2f(v[e]) * sc);
    return r;
}

// ---------------------------------------------------------------------------
// R11: per-block serial prep + grid starvation attack.
//  - k3: no w3 LDS preload/barrier (W3fF fp32 frags staged in k1); per-lane
//    BN2 coeffs (no LDS); rows 32->16 => 1280 blocks (was 640).
//  - k4: no fw1 preload/transform (W1rF fp32 frags staged in k1); 256 blocks
//    x 64 thr (was 128 x 128 = half the CUs idle).
//  - k2: output cols split in half => 896 blocks (was 448); acc/LDS halve.
//  - k1 conv, kSa unchanged; k1 y==9 staging adds W3fF/W1rF (concurrent).
// All weight math stays fp32 until the same f2bf points as before =>
// numerics identical.
// MFMA 16x16x32 bf16 layouts: A[m][k]: m=l&15, k=(l>>4)*8+e; B[k][n]: n=l&15;
// C/D: row=(l>>4)*4+r, col=l&15.
// ---------------------------------------------------------------------------

__global__ void __launch_bounds__(256) kSa(const float* __restrict__ w1,
                                           unsigned short* __restrict__ W1f,
                                           float* __restrict__ stats) {
    int gid = blockIdx.x * 256 + threadIdx.x;   // grid 864*256 == 221184 exactly
    if (gid < 256) stats[gid] = 0.f;
    // W1f: 9*16*3*512
    int j  = gid / 24576;
    int r  = gid % 24576;
    int T  = r / 1536;
    int r2 = r % 1536;
    int ks = r2 / 512;
    int r3 = r2 % 512;
    int ln = r3 >> 3, e = r3 & 7;
    int n  = T * 16 + (ln & 15);
    int kk = ks * 32 + (ln >> 4) * 8 + e;
    int o = n >> 4, t = n & 15;
    int i = kk >> 4, s = kk & 15;
    int h = 1 << j;
    int d = s - t;
    float val = 0.f;
    if (d >= -3 * h && d <= 3 * h) {
        float df = (float)d / (float)h;
        #pragma unroll
        for (int m = 0; m < 7; ++m) {
            float hat = fmaxf(0.f, 1.f - fabsf(df - (float)(m - 3)));
            val += w1[(o * 6 + i) * 7 + m] * hat;
        }
        val /= (float)h;
    }
    W1f[gid] = f2bf(val);
}

__global__ void __launch_bounds__(256) k1(const float* __restrict__ x,
                                          const unsigned short* __restrict__ W1f,
                                          const float* __restrict__ w2,
                                          const float* __restrict__ w3,
                                          const float* __restrict__ fw1,
                                          unsigned short* __restrict__ p1,
                                          unsigned short* __restrict__ W2r,
                                          float* __restrict__ S,
                                          float* __restrict__ W3fF,
                                          float* __restrict__ W1rF,
                                          float* __restrict__ stats1, int B) {
    __shared__ float z[32 * 276];            // stride 276: 2-way-free banks
    __shared__ float lsS[256], lsQ[256];
    int tid = threadIdx.x;

    if (blockIdx.y == 9) {                   // staging blocks (concurrent)
        int base = blockIdx.x * 256 + tid;   // 0..32767 (128 x-blocks)
        for (int g = base; g < 688128; g += 32768) {   // W2r: 7*16*12*512
            int fs = g >> 9;                 // (j*16+T)*12+ks
            int ln = (g >> 3) & 63, e = g & 7;
            int j  = fs / 192;
            int rm = fs % 192;
            int T  = rm / 12, ks = rm % 12;
            int col = T * 16 + (ln & 15);
            int k   = ks * 32 + (ln >> 4) * 8 + e;
            int o = col >> 3, t = col & 7;
            int ic = k >> 3, s = k & 7;
            int i = ic / 3, c = ic % 3;
            int h = 1 << j;
            int d = s - t;
            float raw = 0.f;
            if (d >= -h && d <= h) {
                float df = (float)d / (float)h;
                #pragma unroll
                for (int m = 0; m < 3; ++m) {
                    float hat = fmaxf(0.f, 1.f - fabsf(df - (float)(m - 1)));
                    raw += w2[((o * 16 + i) * 3 + c) * 3 + m] * hat;
                }
                raw /= (float)h;
            }
            W2r[g] = f2bf(raw);
        }
        for (int g = base; g < 28672; g += 32768) {    // S: 7*16*256
            int j = g >> 12;
            int r = g & 4095;
            int i = r >> 8;
            int col = r & 255;
            int o = col >> 3, t = col & 7;
            int h = 1 << j;
            float acc = 0.f;
            #pragma unroll
            for (int c = 0; c < 3; ++c) {
                const float* wr = &w2[((o * 16 + i) * 3 + c) * 3];
                #pragma unroll
                for (int s = 0; s < 8; ++s) {
                    int d = s - t;
                    if (d >= -h && d <= h) {
                        float df = (float)d / (float)h;
                        float raw = 0.f;
                        #pragma unroll
                        for (int m = 0; m < 3; ++m) {
                            float hat = fmaxf(0.f, 1.f - fabsf(df - (float)(m - 1)));
                            raw += wr[m] * hat;
                        }
                        acc += raw / (float)h;
                    }
                }
            }
            S[g] = acc;
        }
        for (int g = base; g < 6144; g += 32768) {     // W3fF: w3 frag order fp32
            int e = g & 7, ln = (g >> 3) & 63, fo = g >> 9;
            int kf = fo >> 2, og = fo & 3;
            int o = og * 16 + (ln & 15);
            int i = (ln >> 4) * 8 + e;
            W3fF[g] = w3[(o * 32 + i) * 3 + kf];
        }
        for (int g = base; g < 5120; g += 32768) {     // W1rF: fw1 frag order fp32
            int e = g & 7, ln = (g >> 3) & 63, fo = g >> 9;
            int jj = fo >> 1, ks = fo & 1;
            int n = ln & 15;
            int oo = ks * 32 + (ln >> 4) * 8 + e;
            W1rF[g] = fw1[n * 320 + oo * 5 + jj];
        }
        return;
    }

    int j = blockIdx.y;
    int wav = tid >> 6, lane = tid & 63;
    int quad = lane >> 4, l15 = lane & 15;
    int msub = wav & 1, nh = wav >> 1;
    int b0 = blockIdx.x * 32;
    floatx4 acc[8];
    #pragma unroll
    for (int T = 0; T < 8; ++T) acc[T] = floatx4{0.f, 0.f, 0.f, 0.f};
    const float* xr = x + (size_t)(b0 + msub * 16 + l15) * 96;
    const short8* Bj = (const short8*)W1f + (size_t)(j * 16) * 3 * 64;
    #pragma unroll
    for (int ks = 0; ks < 3; ++ks) {
        int k0 = ks * 32 + quad * 8;
        floatx4 v0 = *(const floatx4*)(xr + k0);
        floatx4 v1 = *(const floatx4*)(xr + k0 + 4);
        short8 a;
        #pragma unroll
        for (int e = 0; e < 4; ++e) {
            a[e]     = (short)f2bf(v0[e]);
            a[e + 4] = (short)f2bf(v1[e]);
        }
        #pragma unroll
        for (int T = 0; T < 8; ++T) {
            short8 b = Bj[((nh * 8 + T) * 3 + ks) * 64 + lane];
            acc[T] = __builtin_amdgcn_mfma_f32_16x16x32_bf16(a, b, acc[T], 0, 0, 0);
        }
    }
    #pragma unroll
    for (int T = 0; T < 8; ++T) {
        int col = (nh * 8 + T) * 16 + l15;
        int rb  = msub * 16 + quad * 4;
        #pragma unroll
        for (int r = 0; r < 4; ++r) z[(rb + r) * 276 + col] = acc[T][r];
    }
    __syncthreads();
    float psum = 0.f, pss = 0.f;
    #pragma unroll
    for (int i = 0; i < 2; ++i) {
        int u = tid + 256 * i;
        int row = u >> 4, o = u & 15;
        const float* zr = &z[row * 276 + o * 16];
        floatx4 q0 = ((const floatx4*)zr)[0];
        floatx4 q1 = ((const floatx4*)zr)[1];
        floatx4 q2 = ((const floatx4*)zr)[2];
        floatx4 q3 = ((const floatx4*)zr)[3];
        float t[16] = {q0[0], q0[1], q0[2], q0[3], q1[0], q1[1], q1[2], q1[3],
                       q2[0], q2[1], q2[2], q2[3], q3[0], q3[1], q3[2], q3[3]};
        short8 pk;
        #pragma unroll
        for (int tp = 0; tp < 8; ++tp) {
            int lo = (tp == 0) ? 0 : 2 * tp - 1;
            int hi = (tp == 7) ? 15 : 2 * tp + 2;
            float m = t[lo];
            for (int tt = lo + 1; tt <= hi; ++tt) m = fmaxf(m, t[tt]);
            m = fmaxf(m, 0.f);
            pk[tp] = (short)f2bf(m);
            psum += m; pss += m * m;
        }
        *(short8*)(p1 + ((size_t)j * B + b0 + row) * 128 + o * 8) = pk;
    }
    lsS[(tid & 15) * 16 + (tid >> 4)] = psum;
    lsQ[(tid & 15) * 16 + (tid >> 4)] = pss;
    __syncthreads();
    if (tid < 32) {
        int o = tid & 15;
        const float* src = (tid < 16) ? lsS : lsQ;
        float s = 0.f;
        #pragma unroll
        for (int g = 0; g < 16; ++g) s += src[o * 16 + g];
        atomicAdd(&stats1[(tid < 16 ? 0 : 16) + o], s);
    }
}

// k2: blockIdx.y = j*2+ch (ch = column half). 896 blocks.
__global__ void __launch_bounds__(256) k2(const unsigned short* __restrict__ p1,
                                          const unsigned short* __restrict__ W2r,
                                          const float* __restrict__ S,
                                          const float* __restrict__ g1,
                                          const float* __restrict__ b1,
                                          const float* __restrict__ stats1,
                                          unsigned short* __restrict__ p2s,
                                          float* __restrict__ stats2,
                                          float invN1, int B) {
    __shared__ float z[32 * 132];
    __shared__ float lsS[512], lsQ[512];
    __shared__ float a1s[16], d1s[16], bias2L[256];
    int tid = threadIdx.x;
    int j = blockIdx.y >> 1, ch = blockIdx.y & 1;
    int wav = tid >> 6, lane = tid & 63;
    int quad = lane >> 4, l15 = lane & 15;
    int nh = wav & 1, mp = wav >> 1;
    int b0 = blockIdx.x * 64, m0 = b0 + mp * 32;
    if (tid < 16) {
        float mu  = stats1[tid] * invN1;
        float var = stats1[16 + tid] * invN1 - mu * mu;
        float rs  = rsqrtf(var + EPS);
        a1s[tid] = g1[tid] * rs;
        d1s[tid] = b1[tid] - mu * a1s[tid];
    }
    __syncthreads();
    {   // bias2L[col] = sum_i d1[i]*S[j][i][col], coalesced over col=tid
        float s = 0.f;
        const float* Sj = S + (size_t)j * 4096;
        #pragma unroll
        for (int i = 0; i < 16; ++i) s = fmaf(d1s[i], Sj[i * 256 + tid], s);
        bias2L[tid] = s;
    }
    __syncthreads();                         // bias2L is read cross-thread below
    float biasv[4];
    #pragma unroll
    for (int T = 0; T < 4; ++T)
        biasv[T] = bias2L[(ch * 8 + nh * 4 + T) * 16 + l15];
    floatx4 acc[2][4];
    #pragma unroll
    for (int mi = 0; mi < 2; ++mi)
        #pragma unroll
        for (int T = 0; T < 4; ++T) acc[mi][T] = floatx4{0.f, 0.f, 0.f, 0.f};
    const short8* Bj = (const short8*)W2r + (size_t)(j * 16) * 12 * 64;
    #pragma unroll
    for (int ks = 0; ks < 12; ++ks) {
        int icq = ks * 4 + quad;
        int i = icq / 3, c = icq - i * 3;
        float a1v = a1s[i];
        const unsigned short* ap = p1 + ((size_t)(j + c) * B + m0 + l15) * 128 + i * 8;
        short8 a0 = scale8(*(const short8*)ap, a1v);
        short8 a1 = scale8(*(const short8*)(ap + 2048), a1v);
        #pragma unroll
        for (int T = 0; T < 4; ++T) {
            short8 b = Bj[((ch * 8 + nh * 4 + T) * 12 + ks) * 64 + lane];
            acc[0][T] = __builtin_amdgcn_mfma_f32_16x16x32_bf16(a0, b, acc[0][T], 0, 0, 0);
            acc[1][T] = __builtin_amdgcn_mfma_f32_16x16x32_bf16(a1, b, acc[1][T], 0, 0, 0);
        }
    }
    float psum[2] = {0.f, 0.f}, pss[2] = {0.f, 0.f};
    for (int pass = 0; pass < 2; ++pass) {
        __syncthreads();
        if (mp == pass) {
            #pragma unroll
            for (int T = 0; T < 4; ++T) {
                int colloc = (nh * 4 + T) * 16 + l15;
                #pragma unroll
                for (int mi = 0; mi < 2; ++mi) {
                    int rb = mi * 16 + quad * 4;
                    #pragma unroll
                    for (int r = 0; r < 4; ++r)
                        z[(rb + r) * 132 + colloc] = acc[mi][T][r] + biasv[T];
                }
            }
        }
        __syncthreads();
        {
            int opr = tid & 7, row = tid >> 3;        // 32 rows x 8 o-pairs
            const float* zr = &z[row * 132 + opr * 16];
            floatx4 q0 = ((const floatx4*)zr)[0];
            floatx4 q1 = ((const floatx4*)zr)[1];
            floatx4 q2 = ((const floatx4*)zr)[2];
            floatx4 q3 = ((const floatx4*)zr)[3];
            float ta[8] = {q0[0], q0[1], q0[2], q0[3], q1[0], q1[1], q1[2], q1[3]};
            float tb[8] = {q2[0], q2[1], q2[2], q2[3], q3[0], q3[1], q3[2], q3[3]};
            int rowg = pass * 32 + row;
            #pragma unroll
            for (int tp = 0; tp < 4; ++tp) {
                int lo = (tp == 0) ? 0 : 2 * tp - 1;
                int hi = (tp == 3) ? 7 : 2 * tp + 2;
                float m0v = ta[lo], m1v = tb[lo];
                for (int tt = lo + 1; tt <= hi; ++tt) {
                    m0v = fmaxf(m0v, ta[tt]); m1v = fmaxf(m1v, tb[tt]);
                }
                m0v = fmaxf(m0v, 0.f); m1v = fmaxf(m1v, 0.f);
                psum[0] += m0v; pss[0] += m0v * m0v;
                psum[1] += m1v; pss[1] += m1v * m1v;
                unsigned pk = (unsigned)f2bf(m0v) | ((unsigned)f2bf(m1v) << 16);
                *(unsigned*)(p2s + ((size_t)(j * 4 + tp) * B + b0 + rowg) * 32
                             + ch * 16 + opr * 2) = pk;
            }
        }
    }
    {
        int opr = tid & 7, row = tid >> 3;
        lsS[(opr * 2 + 0) * 32 + row] = psum[0];
        lsS[(opr * 2 + 1) * 32 + row] = psum[1];
        lsQ[(opr * 2 + 0) * 32 + row] = pss[0];
        lsQ[(opr * 2 + 1) * 32 + row] = pss[1];
    }
    __syncthreads();
    if (tid < 32) {
        int oloc = tid & 15;
        const float* src = (tid < 16) ? lsS : lsQ;
        float s = 0.f;
        #pragma unroll
        for (int r = 0; r < 32; ++r) s += src[oloc * 32 + r];
        atomicAdd(&stats2[(tid < 16 ? 0 : 32) + ch * 16 + oloc], s);
    }
}

// k3: 16-row tiles, no w3 LDS preload, per-lane BN2 coeffs. 1280 blocks.
__global__ void __launch_bounds__(256) k3(const unsigned short* __restrict__ p2s,
                                          const float* __restrict__ W3fF,
                                          const float* __restrict__ g2,
                                          const float* __restrict__ b2,
                                          const float* __restrict__ stats2,
                                          unsigned short* __restrict__ act3,
                                          float* __restrict__ stats3,
                                          float invN2, int B) {
    __shared__ unsigned short atile[16][72];
    __shared__ float lsS[1024], lsQ[1024];
    int tid = threadIdx.x, j = blockIdx.y, b0 = blockIdx.x * 16;
    int og = tid >> 6, lane = tid & 63;
    int quad = lane >> 4, l15 = lane & 15;
    int i0 = quad * 8;
    // per-lane BN2 coefficients for the lane's 8 i-channels (no LDS/barrier)
    floatx4 sm0 = *(const floatx4*)&stats2[i0];
    floatx4 sm1 = *(const floatx4*)&stats2[i0 + 4];
    floatx4 sq0 = *(const floatx4*)&stats2[32 + i0];
    floatx4 sq1 = *(const floatx4*)&stats2[32 + i0 + 4];
    floatx4 gg0 = *(const floatx4*)&g2[i0];
    floatx4 gg1 = *(const floatx4*)&g2[i0 + 4];
    floatx4 bv0 = *(const floatx4*)&b2[i0];
    floatx4 bv1 = *(const floatx4*)&b2[i0 + 4];
    float a2v[8], d2v[8];
    #pragma unroll
    for (int e = 0; e < 4; ++e) {
        float mu = sm0[e] * invN2;
        float var = sq0[e] * invN2 - mu * mu;
        float rs = rsqrtf(var + EPS);
        a2v[e] = gg0[e] * rs; d2v[e] = bv0[e] - mu * a2v[e];
        mu = sm1[e] * invN2;
        var = sq1[e] * invN2 - mu * mu;
        rs = rsqrtf(var + EPS);
        a2v[e + 4] = gg1[e] * rs; d2v[e + 4] = bv1[e] - mu * a2v[e + 4];
    }
    float biasacc = 0.f;
    short8 af[3];
    #pragma unroll
    for (int kf = 0; kf < 3; ++kf) {
        const float* wp = &W3fF[((size_t)(kf * 4 + og) * 64 + lane) * 8];
        floatx4 w0 = ((const floatx4*)wp)[0];
        floatx4 w1 = ((const floatx4*)wp)[1];
        float wr[8] = {w0[0], w0[1], w0[2], w0[3], w1[0], w1[1], w1[2], w1[3]};
        short8 v;
        #pragma unroll
        for (int e = 0; e < 8; ++e) {
            v[e] = (short)f2bf(wr[e] * a2v[e]);
            biasacc = fmaf(wr[e], d2v[e], biasacc);
        }
        af[kf] = v;
    }
    biasacc += __shfl_xor(biasacc, 16, 64);
    biasacc += __shfl_xor(biasacc, 32, 64);
    float brow[4];
    #pragma unroll
    for (int r = 0; r < 4; ++r) brow[r] = __shfl(biasacc, quad * 4 + r, 64);
    float inv = 1.f / (float)(1 << j);
    float psum[4] = {0.f, 0.f, 0.f, 0.f}, pss[4] = {0.f, 0.f, 0.f, 0.f};
    floatx4 aL0 = {0.f, 0.f, 0.f, 0.f};
    floatx4 aL1 = {0.f, 0.f, 0.f, 0.f};
    floatx4 aL2 = {0.f, 0.f, 0.f, 0.f};
    #pragma unroll
    for (int c = 0; c < 3; ++c) {
        const unsigned short* base =
            p2s + ((size_t)((j + c) * 4) * B + b0 + l15) * 32 + quad * 8;
        short8 f0 = *(const short8*)base;
        short8 f1 = *(const short8*)(base + (size_t)B * 32);
        short8 f2v = *(const short8*)(base + (size_t)2 * B * 32);
        aL0 = __builtin_amdgcn_mfma_f32_16x16x32_bf16(af[c], f0, aL0, 0, 0, 0);
        aL1 = __builtin_amdgcn_mfma_f32_16x16x32_bf16(af[c], f1, aL1, 0, 0, 0);
        aL2 = __builtin_amdgcn_mfma_f32_16x16x32_bf16(af[c], f2v, aL2, 0, 0, 0);
    }
    #pragma unroll
    for (int r = 0; r < 4; ++r) {
        float vm = fmaxf(fmaxf(aL0[r], aL1[r]), aL2[r]);
        float v  = fmaxf((vm + brow[r]) * inv, 0.f);
        atile[l15][og * 16 + quad * 4 + r] = f2bf(v);
        psum[r] += v; pss[r] += v * v;
    }
    #pragma unroll
    for (int r = 0; r < 4; ++r) {
        lsS[(og * 16 + quad * 4 + r) * 16 + l15] = psum[r];
        lsQ[(og * 16 + quad * 4 + r) * 16 + l15] = pss[r];
    }
    __syncthreads();
    if (tid < 128) {
        int row = tid >> 3, oct = tid & 7;
        *(short8*)(act3 + ((size_t)j * B + b0 + row) * 64 + oct * 8) =
            *(const short8*)&atile[row][oct * 8];
    }
    if (tid < 128) {
        int oo = tid & 63;
        const float* src = (tid < 64) ? lsS : lsQ;
        float s = 0.f;
        #pragma unroll
        for (int g = 0; g < 16; ++g) s += src[oo * 16 + g];
        atomicAdd(&stats3[(tid < 64 ? 0 : 64) + oo], s);
    }
}

// k4: 256 blocks x 64 threads (1 wave); weights pre-staged in frag order.
__global__ void __launch_bounds__(64) k4(const unsigned short* __restrict__ act3,
                                         const float* __restrict__ W1rF,
                                         const float* __restrict__ g3,
                                         const float* __restrict__ b3,
                                         const float* __restrict__ stats3,
                                         const float* __restrict__ fw1,
                                         const float* __restrict__ fb1,
                                         const float* __restrict__ fw2,
                                         const float* __restrict__ fb2,
                                         const float* __restrict__ fw3,
                                         const float* __restrict__ fb3,
                                         float* __restrict__ out,
                                         float invN3, int B) {
    __shared__ float a3s[64], d3s[64], fb1f[16], tmp[4][16];
    __shared__ float fw2s[256], fw3s[272], fb2s[16], fb3s[17];
    __shared__ float hbuf[16][17];
    int tid = threadIdx.x;                   // one wave: tid == lane
    int quad = tid >> 4, l15 = tid & 15;
    {
        float mu  = stats3[tid] * invN3;
        float var = stats3[64 + tid] * invN3 - mu * mu;
        float rs  = rsqrtf(var + EPS);
        float a   = g3[tid] * rs;
        a3s[tid] = a;
        d3s[tid] = b3[tid] - mu * a;
    }
    #pragma unroll
    for (int u = 0; u < 4; ++u) fw2s[tid + u * 64] = fw2[tid + u * 64];
    for (int idx = tid; idx < 272; idx += 64) fw3s[idx] = fw3[idx];
    if (tid < 16) fb2s[tid] = fb2[tid];
    if (tid < 17) fb3s[tid] = fb3[tid];
    __syncthreads();
    {   // fb1f partials (overlaps with MFMA loads below in scheduler)
        int f = tid & 15, ch = tid >> 4;
        float s = 0.f;
        for (int u = 0; u < 80; ++u) {
            int n = ch * 80 + u;
            s = fmaf(fw1[f * 320 + n], d3s[n / 5], s);
        }
        tmp[ch][f] = s;
    }
    float a3v[2][8];
    #pragma unroll
    for (int ks = 0; ks < 2; ++ks)
        #pragma unroll
        for (int e = 0; e < 8; ++e) a3v[ks][e] = a3s[ks * 32 + quad * 8 + e];
    int mt = blockIdx.x;
    floatx4 acc = {0.f, 0.f, 0.f, 0.f};
    #pragma unroll
    for (int jj = 0; jj < 5; ++jj)
        #pragma unroll
        for (int ks = 0; ks < 2; ++ks) {
            short8 a = *(const short8*)(act3 +
                ((size_t)jj * B + mt * 16 + l15) * 64 + ks * 32 + quad * 8);
            const float* wp = &W1rF[((size_t)(jj * 2 + ks) * 64 + tid) * 8];
            floatx4 w0 = ((const floatx4*)wp)[0];
            floatx4 w1 = ((const floatx4*)wp)[1];
            short8 b;
            #pragma unroll
            for (int e = 0; e < 4; ++e) {
                b[e]     = (short)f2bf(w0[e] * a3v[ks][e]);
                b[e + 4] = (short)f2bf(w1[e] * a3v[ks][e + 4]);
            }
            acc = __builtin_amdgcn_mfma_f32_16x16x32_bf16(a, b, acc, 0, 0, 0);
        }
    __syncthreads();
    if (tid < 16) fb1f[tid] = fb1[tid] + tmp[0][tid] + tmp[1][tid]
                            + tmp[2][tid] + tmp[3][tid];
    __syncthreads();
    #pragma unroll
    for (int r = 0; r < 4; ++r) hbuf[quad * 4 + r][l15] = acc[r] + fb1f[l15];
    __syncthreads();
    if (tid < 16) {
        int row = l15;
        float hv[16];
        #pragma unroll
        for (int n = 0; n < 16; ++n) hv[n] = hbuf[row][n];
        float h2[16];
        #pragma unroll
        for (int f2 = 0; f2 < 16; ++f2) {
            float s = fb2s[f2];
            #pragma unroll
            for (int n = 0; n < 16; ++n) s = fmaf(fw2s[f2 * 16 + n], hv[n], s);
            h2[f2] = s;
        }
        float* orow = out + (size_t)(mt * 16 + row) * 17;
        #pragma unroll
        for (int f3 = 0; f3 < 17; ++f3) {
            float s = fb3s[f3];
            #pragma unroll
            for (int n = 0; n < 16; ++n) s = fmaf(fw3s[f3 * 16 + n], h2[n], s);
            orow[f3] = s;
        }
    }
}

extern "C" void kernel_launch(void* const* d_in, const int* in_sizes, int n_in,
                              void* d_out, int out_size, void* d_ws, size_t ws_size,
                              hipStream_t stream) {
    (void)n_in; (void)out_size; (void)ws_size;
    const float* x   = (const float*)d_in[0];
    const float* w1  = (const float*)d_in[1];
    const float* w2  = (const float*)d_in[2];
    const float* w3  = (const float*)d_in[3];
    const float* g1  = (const float*)d_in[4];
    const float* b1  = (const float*)d_in[5];
    const float* g2  = (const float*)d_in[6];
    const float* b2  = (const float*)d_in[7];
    const float* g3  = (const float*)d_in[8];
    const float* b3  = (const float*)d_in[9];
    const float* fw1 = (const float*)d_in[10];
    const float* fb1 = (const float*)d_in[11];
    const float* fw2 = (const float*)d_in[12];
    const float* fb2 = (const float*)d_in[13];
    const float* fw3 = (const float*)d_in[14];
    const float* fb3 = (const float*)d_in[15];
    float* out = (float*)d_out;

    int B = in_sizes[0] / 96;                 // 4096

    char* wsb = (char*)d_ws;
    float*          stats = (float*)wsb;                      // 256 f
    unsigned short* W1f   = (unsigned short*)(wsb + 1024);    // 221184 us
    unsigned short* W2r   = W1f + 221184;                     // 688128 us
    float*          S     = (float*)(W2r + 688128);           // 28672 f
    float*          W3fF  = S + 28672;                        // 6144 f
    float*          W1rF  = W3fF + 6144;                      // 5120 f
    unsigned short* p1    = (unsigned short*)(W1rF + 5120);   // 9*B*128 us
    unsigned short* p2s   = p1 + (size_t)9 * B * 128;         // 28*B*32 us
    unsigned short* act3  = p2s + (size_t)28 * B * 32;        // 5*B*64 us

    float* stats1 = stats;
    float* stats2 = stats + 32;
    float* stats3 = stats + 96;

    float invN1 = 1.f / (float)(B * 72);
    float invN2 = 1.f / (float)(B * 28);
    float invN3 = 1.f / (float)(B * 5);

    kSa<<<864, 256, 0, stream>>>(w1, W1f, stats);
    k1<<<dim3(B / 32, 10), 256, 0, stream>>>(x, W1f, w2, w3, fw1, p1, W2r, S,
                                             W3fF, W1rF, stats1, B);
    k2<<<dim3(B / 64, 14), 256, 0, stream>>>(p1, W2r, S, g1, b1, stats1, p2s, stats2,
                                             invN1, B);
    k3<<<dim3(B / 16, 5), 256, 0, stream>>>(p2s, W3fF, g2, b2, stats2, act3, stats3,
                                            invN2, B);
    k4<<<B / 16, 64, 0, stream>>>(act3, W1rF, g3, b3, stats3, fw1, fb1, fw2, fb2,
                                  fw3, fb3, out, invN3, B);
}

// Round 4
// 176.881 us; speedup vs baseline: 1.0751x; 1.0751x over previous
//
#include <hip/hip_runtime.h>

#define EPS 2e-5f

using short8  = __attribute__((ext_vector_type(8))) short;
using floatx4 = __attribute__((ext_vector_type(4))) float;

// round-to-nearest-even fp32 -> bf16 bits
static __device__ inline unsigned short f2bf(float f) {
    unsigned u = __float_as_uint(f);
    u += 0x7fffu + ((u >> 16) & 1u);
    return (unsigned short)(u >> 16);
}
static __device__ inline float bf2f(short s) {
    return __uint_as_float(((unsigned)(unsigned short)s) << 16);
}
static __device__ inline short8 scale8(short8 v, float sc) {
    short8 r;
    #pragma unroll
    for (int e = 0; e < 8; ++e) r[e] = (short)f2bf(bf2f(v[e]) * sc);
    return r;
}

// ---------------------------------------------------------------------------
// R12 = R2 structure (proven 174us; R3's grid changes reverted) + chain cuts:
//  - k3: no w3 LDS preload/barrier (W3fF fp32 frags), per-lane BN2 coeffs
//        (no LDS/barrier). 640 blocks, 32-row tiles (R2 grid).
//  - k4: no fw1L preload / W1s transform / barrier (W1rF fp32 frags);
//        128 blocks x 128 thr (R2 grid).
//  - kSa/k1/k2 byte-identical to R2; k1 y==9 staging adds W3fF/W1rF.
// All arithmetic hits identical f2bf points => numerics unchanged.
// MFMA 16x16x32 bf16 layouts: A[m][k]: m=l&15, k=(l>>4)*8+e; B[k][n]: n=l&15;
// C/D: row=(l>>4)*4+r, col=l&15.
// ---------------------------------------------------------------------------

__global__ void __launch_bounds__(256) kSa(const float* __restrict__ w1,
                                           unsigned short* __restrict__ W1f,
                                           float* __restrict__ stats) {
    int gid = blockIdx.x * 256 + threadIdx.x;   // grid 864*256 == 221184 exactly
    if (gid < 256) stats[gid] = 0.f;
    // W1f: 9*16*3*512
    int j  = gid / 24576;
    int r  = gid % 24576;
    int T  = r / 1536;
    int r2 = r % 1536;
    int ks = r2 / 512;
    int r3 = r2 % 512;
    int ln = r3 >> 3, e = r3 & 7;
    int n  = T * 16 + (ln & 15);
    int kk = ks * 32 + (ln >> 4) * 8 + e;
    int o = n >> 4, t = n & 15;
    int i = kk >> 4, s = kk & 15;
    int h = 1 << j;
    int d = s - t;
    float val = 0.f;
    if (d >= -3 * h && d <= 3 * h) {
        float df = (float)d / (float)h;
        #pragma unroll
        for (int m = 0; m < 7; ++m) {
            float hat = fmaxf(0.f, 1.f - fabsf(df - (float)(m - 3)));
            val += w1[(o * 6 + i) * 7 + m] * hat;
        }
        val /= (float)h;
    }
    W1f[gid] = f2bf(val);
}

__global__ void __launch_bounds__(256) k1(const float* __restrict__ x,
                                          const unsigned short* __restrict__ W1f,
                                          const float* __restrict__ w2,
                                          const float* __restrict__ w3,
                                          const float* __restrict__ fw1,
                                          unsigned short* __restrict__ p1,
                                          unsigned short* __restrict__ W2r,
                                          float* __restrict__ S,
                                          float* __restrict__ W3fF,
                                          float* __restrict__ W1rF,
                                          float* __restrict__ stats1, int B) {
    __shared__ float z[32 * 276];            // stride 276: 2-way-free banks
    __shared__ float lsS[256], lsQ[256];
    int tid = threadIdx.x;

    if (blockIdx.y == 9) {                   // staging blocks (concurrent)
        int base = blockIdx.x * 256 + tid;   // 0..32767 (128 x-blocks)
        for (int g = base; g < 688128; g += 32768) {   // W2r: 7*16*12*512
            int fs = g >> 9;                 // (j*16+T)*12+ks
            int ln = (g >> 3) & 63, e = g & 7;
            int j  = fs / 192;
            int rm = fs % 192;
            int T  = rm / 12, ks = rm % 12;
            int col = T * 16 + (ln & 15);
            int k   = ks * 32 + (ln >> 4) * 8 + e;
            int o = col >> 3, t = col & 7;
            int ic = k >> 3, s = k & 7;
            int i = ic / 3, c = ic % 3;
            int h = 1 << j;
            int d = s - t;
            float raw = 0.f;
            if (d >= -h && d <= h) {
                float df = (float)d / (float)h;
                #pragma unroll
                for (int m = 0; m < 3; ++m) {
                    float hat = fmaxf(0.f, 1.f - fabsf(df - (float)(m - 1)));
                    raw += w2[((o * 16 + i) * 3 + c) * 3 + m] * hat;
                }
                raw /= (float)h;
            }
            W2r[g] = f2bf(raw);
        }
        for (int g = base; g < 28672; g += 32768) {    // S: 7*16*256
            int j = g >> 12;
            int r = g & 4095;
            int i = r >> 8;
            int col = r & 255;
            int o = col >> 3, t = col & 7;
            int h = 1 << j;
            float acc = 0.f;
            #pragma unroll
            for (int c = 0; c < 3; ++c) {
                const float* wr = &w2[((o * 16 + i) * 3 + c) * 3];
                #pragma unroll
                for (int s = 0; s < 8; ++s) {
                    int d = s - t;
                    if (d >= -h && d <= h) {
                        float df = (float)d / (float)h;
                        float raw = 0.f;
                        #pragma unroll
                        for (int m = 0; m < 3; ++m) {
                            float hat = fmaxf(0.f, 1.f - fabsf(df - (float)(m - 1)));
                            raw += wr[m] * hat;
                        }
                        acc += raw / (float)h;
                    }
                }
            }
            S[g] = acc;
        }
        for (int g = base; g < 6144; g += 32768) {     // W3fF: w3 frag order fp32
            int e = g & 7, ln = (g >> 3) & 63, fo = g >> 9;
            int kf = fo >> 2, og = fo & 3;
            int o = og * 16 + (ln & 15);
            int i = (ln >> 4) * 8 + e;
            W3fF[g] = w3[(o * 32 + i) * 3 + kf];
        }
        for (int g = base; g < 5120; g += 32768) {     // W1rF: fw1 frag order fp32
            int e = g & 7, ln = (g >> 3) & 63, fo = g >> 9;
            int jj = fo >> 1, ks = fo & 1;
            int n = ln & 15;
            int oo = ks * 32 + (ln >> 4) * 8 + e;
            W1rF[g] = fw1[n * 320 + oo * 5 + jj];
        }
        return;
    }

    int j = blockIdx.y;
    int wav = tid >> 6, lane = tid & 63;
    int quad = lane >> 4, l15 = lane & 15;
    int msub = wav & 1, nh = wav >> 1;
    int b0 = blockIdx.x * 32;
    floatx4 acc[8];
    #pragma unroll
    for (int T = 0; T < 8; ++T) acc[T] = floatx4{0.f, 0.f, 0.f, 0.f};
    const float* xr = x + (size_t)(b0 + msub * 16 + l15) * 96;
    const short8* Bj = (const short8*)W1f + (size_t)(j * 16) * 3 * 64;
    #pragma unroll
    for (int ks = 0; ks < 3; ++ks) {
        int k0 = ks * 32 + quad * 8;
        floatx4 v0 = *(const floatx4*)(xr + k0);
        floatx4 v1 = *(const floatx4*)(xr + k0 + 4);
        short8 a;
        #pragma unroll
        for (int e = 0; e < 4; ++e) {
            a[e]     = (short)f2bf(v0[e]);
            a[e + 4] = (short)f2bf(v1[e]);
        }
        #pragma unroll
        for (int T = 0; T < 8; ++T) {
            short8 b = Bj[((nh * 8 + T) * 3 + ks) * 64 + lane];
            acc[T] = __builtin_amdgcn_mfma_f32_16x16x32_bf16(a, b, acc[T], 0, 0, 0);
        }
    }
    #pragma unroll
    for (int T = 0; T < 8; ++T) {
        int col = (nh * 8 + T) * 16 + l15;
        int rb  = msub * 16 + quad * 4;
        #pragma unroll
        for (int r = 0; r < 4; ++r) z[(rb + r) * 276 + col] = acc[T][r];
    }
    __syncthreads();
    float psum = 0.f, pss = 0.f;
    #pragma unroll
    for (int i = 0; i < 2; ++i) {
        int u = tid + 256 * i;
        int row = u >> 4, o = u & 15;
        const float* zr = &z[row * 276 + o * 16];
        floatx4 q0 = ((const floatx4*)zr)[0];
        floatx4 q1 = ((const floatx4*)zr)[1];
        floatx4 q2 = ((const floatx4*)zr)[2];
        floatx4 q3 = ((const floatx4*)zr)[3];
        float t[16] = {q0[0], q0[1], q0[2], q0[3], q1[0], q1[1], q1[2], q1[3],
                       q2[0], q2[1], q2[2], q2[3], q3[0], q3[1], q3[2], q3[3]};
        short8 pk;
        #pragma unroll
        for (int tp = 0; tp < 8; ++tp) {
            int lo = (tp == 0) ? 0 : 2 * tp - 1;
            int hi = (tp == 7) ? 15 : 2 * tp + 2;
            float m = t[lo];
            for (int tt = lo + 1; tt <= hi; ++tt) m = fmaxf(m, t[tt]);
            m = fmaxf(m, 0.f);
            pk[tp] = (short)f2bf(m);
            psum += m; pss += m * m;
        }
        *(short8*)(p1 + ((size_t)j * B + b0 + row) * 128 + o * 8) = pk;
    }
    lsS[(tid & 15) * 16 + (tid >> 4)] = psum;
    lsQ[(tid & 15) * 16 + (tid >> 4)] = pss;
    __syncthreads();
    if (tid < 32) {
        int o = tid & 15;
        const float* src = (tid < 16) ? lsS : lsQ;
        float s = 0.f;
        #pragma unroll
        for (int g = 0; g < 16; ++g) s += src[o * 16 + g];
        atomicAdd(&stats1[(tid < 16 ? 0 : 16) + o], s);
    }
}

__global__ void __launch_bounds__(256) k2(const unsigned short* __restrict__ p1,
                                          const unsigned short* __restrict__ W2r,
                                          const float* __restrict__ S,
                                          const float* __restrict__ g1,
                                          const float* __restrict__ b1,
                                          const float* __restrict__ stats1,
                                          unsigned short* __restrict__ p2s,
                                          float* __restrict__ stats2,
                                          float invN1, int B) {
    __shared__ float z[32 * 260];
    __shared__ float lsS[512], lsQ[512];
    __shared__ float a1s[16], d1s[16], bias2L[256];
    int tid = threadIdx.x, j = blockIdx.y;
    int wav = tid >> 6, lane = tid & 63;
    int quad = lane >> 4, l15 = lane & 15;
    int nh = wav & 1, mp = wav >> 1;
    int b0 = blockIdx.x * 64, m0 = b0 + mp * 32;
    if (tid < 16) {
        float mu  = stats1[tid] * invN1;
        float var = stats1[16 + tid] * invN1 - mu * mu;
        float rs  = rsqrtf(var + EPS);
        a1s[tid] = g1[tid] * rs;
        d1s[tid] = b1[tid] - mu * a1s[tid];
    }
    __syncthreads();
    {   // bias2L[col] = sum_i d1[i]*S[j][i][col], coalesced over col=tid
        float s = 0.f;
        const float* Sj = S + (size_t)j * 4096;
        #pragma unroll
        for (int i = 0; i < 16; ++i) s = fmaf(d1s[i], Sj[i * 256 + tid], s);
        bias2L[tid] = s;
    }
    __syncthreads();                         // bias2L is read cross-thread below
    float biasv[8];
    #pragma unroll
    for (int T = 0; T < 8; ++T) biasv[T] = bias2L[(nh * 8 + T) * 16 + l15];
    floatx4 acc[2][8];
    #pragma unroll
    for (int mi = 0; mi < 2; ++mi)
        #pragma unroll
        for (int T = 0; T < 8; ++T) acc[mi][T] = floatx4{0.f, 0.f, 0.f, 0.f};
    const short8* Bj = (const short8*)W2r + (size_t)(j * 16) * 12 * 64;
    #pragma unroll
    for (int ks = 0; ks < 12; ++ks) {
        int icq = ks * 4 + quad;
        int i = icq / 3, c = icq - i * 3;
        float a1v = a1s[i];
        const unsigned short* ap = p1 + ((size_t)(j + c) * B + m0 + l15) * 128 + i * 8;
        short8 a0 = scale8(*(const short8*)ap, a1v);
        short8 a1 = scale8(*(const short8*)(ap + 2048), a1v);
        #pragma unroll
        for (int T = 0; T < 8; ++T) {
            short8 b = Bj[((nh * 8 + T) * 12 + ks) * 64 + lane];
            acc[0][T] = __builtin_amdgcn_mfma_f32_16x16x32_bf16(a0, b, acc[0][T], 0, 0, 0);
            acc[1][T] = __builtin_amdgcn_mfma_f32_16x16x32_bf16(a1, b, acc[1][T], 0, 0, 0);
        }
    }
    float psum[2] = {0.f, 0.f}, pss[2] = {0.f, 0.f};
    for (int pass = 0; pass < 2; ++pass) {
        __syncthreads();
        if (mp == pass) {
            #pragma unroll
            for (int T = 0; T < 8; ++T) {
                int col = (nh * 8 + T) * 16 + l15;
                #pragma unroll
                for (int mi = 0; mi < 2; ++mi) {
                    int rb = mi * 16 + quad * 4;
                    #pragma unroll
                    for (int r = 0; r < 4; ++r)
                        z[(rb + r) * 260 + col] = acc[mi][T][r] + biasv[T];
                }
            }
        }
        __syncthreads();
        #pragma unroll
        for (int i2 = 0; i2 < 2; ++i2) {
            int u = tid + 256 * i2;
            int opr = u & 15, row = u >> 4;
            const float* zr = &z[row * 260 + opr * 16];
            floatx4 q0 = ((const floatx4*)zr)[0];
            floatx4 q1 = ((const floatx4*)zr)[1];
            floatx4 q2 = ((const floatx4*)zr)[2];
            floatx4 q3 = ((const floatx4*)zr)[3];
            float ta[8] = {q0[0], q0[1], q0[2], q0[3], q1[0], q1[1], q1[2], q1[3]};
            float tb[8] = {q2[0], q2[1], q2[2], q2[3], q3[0], q3[1], q3[2], q3[3]};
            int rowg = pass * 32 + row;
            #pragma unroll
            for (int tp = 0; tp < 4; ++tp) {
                int lo = (tp == 0) ? 0 : 2 * tp - 1;
                int hi = (tp == 3) ? 7 : 2 * tp + 2;
                float m0v = ta[lo], m1v = tb[lo];
                for (int tt = lo + 1; tt <= hi; ++tt) {
                    m0v = fmaxf(m0v, ta[tt]); m1v = fmaxf(m1v, tb[tt]);
                }
                m0v = fmaxf(m0v, 0.f); m1v = fmaxf(m1v, 0.f);
                psum[0] += m0v; pss[0] += m0v * m0v;
                psum[1] += m1v; pss[1] += m1v * m1v;
                unsigned pk = (unsigned)f2bf(m0v) | ((unsigned)f2bf(m1v) << 16);
                // direct store: 4B per thread, 16 threads cover 64B contiguous
                *(unsigned*)(p2s + ((size_t)(j * 4 + tp) * B + b0 + rowg) * 32
                             + opr * 2) = pk;
            }
        }
    }
    {
        int o0 = 2 * (tid & 15), g = tid >> 4;
        lsS[o0 * 16 + g] = psum[0]; lsS[(o0 + 1) * 16 + g] = psum[1];
        lsQ[o0 * 16 + g] = pss[0];  lsQ[(o0 + 1) * 16 + g] = pss[1];
    }
    __syncthreads();
    if (tid < 64) {
        int o = tid & 31;
        const float* src = (tid < 32) ? lsS : lsQ;
        float s = 0.f;
        #pragma unroll
        for (int g = 0; g < 16; ++g) s += src[o * 16 + g];
        atomicAdd(&stats2[(tid < 32 ? 0 : 32) + o], s);
    }
}

// k3: R2 grid (640 blocks, 32-row tiles); no w3 LDS preload; per-lane BN2.
__global__ void __launch_bounds__(256) k3(const unsigned short* __restrict__ p2s,
                                          const float* __restrict__ W3fF,
                                          const float* __restrict__ g2,
                                          const float* __restrict__ b2,
                                          const float* __restrict__ stats2,
                                          unsigned short* __restrict__ act3,
                                          float* __restrict__ stats3,
                                          float invN2, int B) {
    __shared__ unsigned short atile[32][72];
    __shared__ float lsS[1024], lsQ[1024];
    int tid = threadIdx.x, j = blockIdx.y, b0 = blockIdx.x * 32;
    int og = tid >> 6, lane = tid & 63;
    int quad = lane >> 4, l15 = lane & 15;
    int i0 = quad * 8;
    // per-lane BN2 coefficients for the lane's 8 i-channels (no LDS/barrier)
    floatx4 sm0 = *(const floatx4*)&stats2[i0];
    floatx4 sm1 = *(const floatx4*)&stats2[i0 + 4];
    floatx4 sq0 = *(const floatx4*)&stats2[32 + i0];
    floatx4 sq1 = *(const floatx4*)&stats2[32 + i0 + 4];
    floatx4 gg0 = *(const floatx4*)&g2[i0];
    floatx4 gg1 = *(const floatx4*)&g2[i0 + 4];
    floatx4 bv0 = *(const floatx4*)&b2[i0];
    floatx4 bv1 = *(const floatx4*)&b2[i0 + 4];
    float a2v[8], d2v[8];
    #pragma unroll
    for (int e = 0; e < 4; ++e) {
        float mu = sm0[e] * invN2;
        float var = sq0[e] * invN2 - mu * mu;
        float rs = rsqrtf(var + EPS);
        a2v[e] = gg0[e] * rs; d2v[e] = bv0[e] - mu * a2v[e];
        mu = sm1[e] * invN2;
        var = sq1[e] * invN2 - mu * mu;
        rs = rsqrtf(var + EPS);
        a2v[e + 4] = gg1[e] * rs; d2v[e + 4] = bv1[e] - mu * a2v[e + 4];
    }
    float biasacc = 0.f;
    short8 af[3];
    #pragma unroll
    for (int kf = 0; kf < 3; ++kf) {
        const float* wp = &W3fF[((size_t)(kf * 4 + og) * 64 + lane) * 8];
        floatx4 w0 = ((const floatx4*)wp)[0];
        floatx4 w1 = ((const floatx4*)wp)[1];
        float wr[8] = {w0[0], w0[1], w0[2], w0[3], w1[0], w1[1], w1[2], w1[3]};
        short8 v;
        #pragma unroll
        for (int e = 0; e < 8; ++e) {
            v[e] = (short)f2bf(wr[e] * a2v[e]);
            biasacc = fmaf(wr[e], d2v[e], biasacc);
        }
        af[kf] = v;
    }
    biasacc += __shfl_xor(biasacc, 16, 64);
    biasacc += __shfl_xor(biasacc, 32, 64);
    float brow[4];
    #pragma unroll
    for (int r = 0; r < 4; ++r) brow[r] = __shfl(biasacc, quad * 4 + r, 64);
    float inv = 1.f / (float)(1 << j);
    float psum[4] = {0.f, 0.f, 0.f, 0.f}, pss[4] = {0.f, 0.f, 0.f, 0.f};
    #pragma unroll
    for (int bt = 0; bt < 2; ++bt) {
        int bb = b0 + bt * 16;
        floatx4 aL0 = {0.f, 0.f, 0.f, 0.f};
        floatx4 aL1 = {0.f, 0.f, 0.f, 0.f};
        floatx4 aL2 = {0.f, 0.f, 0.f, 0.f};
        #pragma unroll
        for (int c = 0; c < 3; ++c) {
            const unsigned short* base =
                p2s + ((size_t)((j + c) * 4) * B + bb + l15) * 32 + quad * 8;
            short8 f0 = *(const short8*)base;
            short8 f1 = *(const short8*)(base + (size_t)B * 32);
            short8 f2v = *(const short8*)(base + (size_t)2 * B * 32);
            aL0 = __builtin_amdgcn_mfma_f32_16x16x32_bf16(af[c], f0, aL0, 0, 0, 0);
            aL1 = __builtin_amdgcn_mfma_f32_16x16x32_bf16(af[c], f1, aL1, 0, 0, 0);
            aL2 = __builtin_amdgcn_mfma_f32_16x16x32_bf16(af[c], f2v, aL2, 0, 0, 0);
        }
        #pragma unroll
        for (int r = 0; r < 4; ++r) {
            float vm = fmaxf(fmaxf(aL0[r], aL1[r]), aL2[r]);
            float v  = fmaxf((vm + brow[r]) * inv, 0.f);
            atile[bt * 16 + l15][og * 16 + quad * 4 + r] = f2bf(v);
            psum[r] += v; pss[r] += v * v;
        }
    }
    #pragma unroll
    for (int r = 0; r < 4; ++r) {
        lsS[(og * 16 + quad * 4 + r) * 16 + l15] = psum[r];
        lsQ[(og * 16 + quad * 4 + r) * 16 + l15] = pss[r];
    }
    __syncthreads();
    {
        int row = tid >> 3, oct = tid & 7;
        *(short8*)(act3 + ((size_t)j * B + b0 + row) * 64 + oct * 8) =
            *(const short8*)&atile[row][oct * 8];
    }
    if (tid < 128) {
        int oo = tid & 63;
        const float* src = (tid < 64) ? lsS : lsQ;
        float s = 0.f;
        #pragma unroll
        for (int g = 0; g < 16; ++g) s += src[oo * 16 + g];
        atomicAdd(&stats3[(tid < 64 ? 0 : 64) + oo], s);
    }
}

// k4: R2 grid (128 blocks x 128 thr); weights from W1rF (no fw1L/W1s staging).
__global__ void __launch_bounds__(128) k4(const unsigned short* __restrict__ act3,
                                          const float* __restrict__ W1rF,
                                          const float* __restrict__ g3,
                                          const float* __restrict__ b3,
                                          const float* __restrict__ stats3,
                                          const float* __restrict__ fw1,
                                          const float* __restrict__ fb1,
                                          const float* __restrict__ fw2,
                                          const float* __restrict__ fb2,
                                          const float* __restrict__ fw3,
                                          const float* __restrict__ fb3,
                                          float* __restrict__ out,
                                          float invN3, int B) {
    __shared__ float a3s[64], d3s[64];
    __shared__ float fw2s[256], fw3s[272], fb2s[16], fb3s[17], fb1f[16], tmp[4][16];
    __shared__ float hbuf[2][16][17];
    int tid = threadIdx.x;
    int wav = tid >> 6, lane = tid & 63;
    int quad = lane >> 4, l15 = lane & 15;
    if (tid < 64) {
        float mu  = stats3[tid] * invN3;
        float var = stats3[64 + tid] * invN3 - mu * mu;
        float rs  = rsqrtf(var + EPS);
        float a   = g3[tid] * rs;
        a3s[tid] = a;
        d3s[tid] = b3[tid] - mu * a;
    }
    if (tid < 16) fb2s[tid] = fb2[tid];
    if (tid < 17) fb3s[tid] = fb3[tid];
    #pragma unroll
    for (int u = 0; u < 2; ++u) fw2s[tid + u * 128] = fw2[tid + u * 128];
    for (int idx = tid; idx < 272; idx += 128) fw3s[idx] = fw3[idx];
    __syncthreads();
    if (tid < 64) {                          // fb1f partials from global fw1
        int f = tid & 15, ch = tid >> 4;
        float s = 0.f;
        for (int u = 0; u < 80; ++u) {
            int n = ch * 80 + u;
            s = fmaf(fw1[f * 320 + n], d3s[n / 5], s);
        }
        tmp[ch][f] = s;
    }
    float a3v[2][8];
    #pragma unroll
    for (int ks = 0; ks < 2; ++ks)
        #pragma unroll
        for (int e = 0; e < 8; ++e) a3v[ks][e] = a3s[ks * 32 + quad * 8 + e];
    int mt = blockIdx.x * 2 + wav;
    floatx4 acc = {0.f, 0.f, 0.f, 0.f};
    #pragma unroll
    for (int jj = 0; jj < 5; ++jj)
        #pragma unroll
        for (int ks = 0; ks < 2; ++ks) {
            short8 a = *(const short8*)(act3 +
                ((size_t)jj * B + mt * 16 + l15) * 64 + ks * 32 + quad * 8);
            const float* wp = &W1rF[((size_t)(jj * 2 + ks) * 64 + lane) * 8];
            floatx4 w0 = ((const floatx4*)wp)[0];
            floatx4 w1 = ((const floatx4*)wp)[1];
            short8 b;
            #pragma unroll
            for (int e = 0; e < 4; ++e) {
                b[e]     = (short)f2bf(w0[e] * a3v[ks][e]);
                b[e + 4] = (short)f2bf(w1[e] * a3v[ks][e + 4]);
            }
            acc = __builtin_amdgcn_mfma_f32_16x16x32_bf16(a, b, acc, 0, 0, 0);
        }
    __syncthreads();
    if (tid < 16) fb1f[tid] = fb1[tid] + tmp[0][tid] + tmp[1][tid]
                            + tmp[2][tid] + tmp[3][tid];
    __syncthreads();
    #pragma unroll
    for (int r = 0; r < 4; ++r) hbuf[wav][quad * 4 + r][l15] = acc[r] + fb1f[l15];
    __syncthreads();
    if (lane < 16) {
        int row = l15;
        float hv[16];
        #pragma unroll
        for (int n = 0; n < 16; ++n) hv[n] = hbuf[wav][row][n];
        float h2[16];
        #pragma unroll
        for (int f2 = 0; f2 < 16; ++f2) {
            float s = fb2s[f2];
            #pragma unroll
            for (int n = 0; n < 16; ++n) s = fmaf(fw2s[f2 * 16 + n], hv[n], s);
            h2[f2] = s;
        }
        float* orow = out + (size_t)(mt * 16 + row) * 17;
        #pragma unroll
        for (int f3 = 0; f3 < 17; ++f3) {
            float s = fb3s[f3];
            #pragma unroll
            for (int n = 0; n < 16; ++n) s = fmaf(fw3s[f3 * 16 + n], h2[n], s);
            orow[f3] = s;
        }
    }
}

extern "C" void kernel_launch(void* const* d_in, const int* in_sizes, int n_in,
                              void* d_out, int out_size, void* d_ws, size_t ws_size,
                              hipStream_t stream) {
    (void)n_in; (void)out_size; (void)ws_size;
    const float* x   = (const float*)d_in[0];
    const float* w1  = (const float*)d_in[1];
    const float* w2  = (const float*)d_in[2];
    const float* w3  = (const float*)d_in[3];
    const float* g1  = (const float*)d_in[4];
    const float* b1  = (const float*)d_in[5];
    const float* g2  = (const float*)d_in[6];
    const float* b2  = (const float*)d_in[7];
    const float* g3  = (const float*)d_in[8];
    const float* b3  = (const float*)d_in[9];
    const float* fw1 = (const float*)d_in[10];
    const float* fb1 = (const float*)d_in[11];
    const float* fw2 = (const float*)d_in[12];
    const float* fb2 = (const float*)d_in[13];
    const float* fw3 = (const float*)d_in[14];
    const float* fb3 = (const float*)d_in[15];
    float* out = (float*)d_out;

    int B = in_sizes[0] / 96;                 // 4096

    char* wsb = (char*)d_ws;
    float*          stats = (float*)wsb;                      // 256 f
    unsigned short* W1f   = (unsigned short*)(wsb + 1024);    // 221184 us
    unsigned short* W2r   = W1f + 221184;                     // 688128 us
    float*          S     = (float*)(W2r + 688128);           // 28672 f
    float*          W3fF  = S + 28672;                        // 6144 f
    float*          W1rF  = W3fF + 6144;                      // 5120 f
    unsigned short* p1    = (unsigned short*)(W1rF + 5120);   // 9*B*128 us
    unsigned short* p2s   = p1 + (size_t)9 * B * 128;         // 28*B*32 us
    unsigned short* act3  = p2s + (size_t)28 * B * 32;        // 5*B*64 us

    float* stats1 = stats;
    float* stats2 = stats + 32;
    float* stats3 = stats + 96;

    float invN1 = 1.f / (float)(B * 72);
    float invN2 = 1.f / (float)(B * 28);
    float invN3 = 1.f / (float)(B * 5);

    kSa<<<864, 256, 0, stream>>>(w1, W1f, stats);
    k1<<<dim3(B / 32, 10), 256, 0, stream>>>(x, W1f, w2, w3, fw1, p1, W2r, S,
                                             W3fF, W1rF, stats1, B);
    k2<<<dim3(B / 64, 7), 256, 0, stream>>>(p1, W2r, S, g1, b1, stats1, p2s, stats2,
                                            invN1, B);
    k3<<<dim3(B / 32, 5), 256, 0, stream>>>(p2s, W3fF, g2, b2, stats2, act3, stats3,
                                            invN2, B);
    k4<<<B / 32, 128, 0, stream>>>(act3, W1rF, g3, b3, stats3, fw1, fb1, fw2, fb2,
                                   fw3, fb3, out, invN3, B);
}